// Round 8
// baseline (114.297 us; speedup 1.0000x reference)
//
#include <hip/hip_runtime.h>

// CrossProductLayer: out[b, f] = t(b, f) * w[f]
//   f in [0,128)    : x[b,f]^2
//   f in [128,256)  : x[b,f-128]
//   f in [256,8384) : x[b,i]*x[b,j]*0.5, (i,j) = triu_indices(128, k=1)[f-256]
// B=16384, F=8384. 549 MB fp32 output -> HBM-write-bound.
//
// R8: persistent 8-tile blocks. Grid = 2048 exactly (8 blocks/CU, no
// residency imbalance). Block = (f-window bx, by); loops tiles rg=by+64k,
// k<8 -> concurrent writes sweep a 68 MB window (R2-like macro locality,
// which R7 showed matters). Per-thread decode ONCE per block (8x amortized);
// next x-tile prefetched into registers while storing the current tile
// (load latency off the critical path); single 16 KB LDS buffer, 2
// barriers/tile. The 33rd f-window (f>=8192) is spread evenly: every block
// does 6 tail stores for rows [wid*8, wid*8+8) at start, overlapping the
// initial prefetch. Exact balance: 262 stores/thread everywhere.
// Store width: dword (empirical winner R2 vs R4); plain stores (no nt).
// fp-exact: same op order as R2 (absmax 0.0 in R2-R7).

constexpr int BATCH = 16384;
constexpr int NIN   = 128;
constexpr int NFEAT = 2 * NIN + NIN * (NIN - 1) / 2;  // 8384
constexpr int TPB   = 256;
constexpr int BROWS = 32;
constexpr int NWIN  = 32;               // main-path f-windows (cover 8192)
constexpr int FMAIN = NWIN * TPB;       // 8192
constexpr int NTAIL = NFEAT - FMAIN;    // 192
constexpr int NBY   = 64;
constexpr int NT    = 8;                // tiles per block; NBY*NT*BROWS = 16384
constexpr int NBLK  = NWIN * NBY;       // 2048

__device__ __forceinline__ int pair_off(int i) { return i * (NIN - 1) - (i * (i - 1)) / 2; }

__device__ __forceinline__ void decode_pair(int p, int& i, int& j) {
    float s = sqrtf((float)(65025 - 8 * p));
    int  ii = (int)((255.0f - s) * 0.5f);
    ii = min(max(ii, 0), NIN - 2);
    while (pair_off(ii + 1) <= p) ++ii;   // exact integer fix-up
    while (pair_off(ii)     >  p) --ii;
    i = ii; j = ii + 1 + (p - pair_off(ii));
}

__global__ __launch_bounds__(TPB) void cpl_kernel(const float* __restrict__ x,
                                                  const float* __restrict__ w,
                                                  float* __restrict__ out) {
    __shared__ float xs[BROWS * NIN];
    const int tid = threadIdx.x;
    const int wid = blockIdx.x;
    const int bx  = wid & (NWIN - 1);   // f-window
    const int by  = wid >> 5;           // row-group phase

    // Per-thread decode, ONCE per block (f < 8192 always; no bound check).
    const int f = bx * TPB + tid;
    int i1, i2, mode;  // 0=square, 1=single, 2=pair
    if (f < NIN)          { i1 = f;       i2 = f;  mode = 0; }
    else if (f < 2 * NIN) { i1 = f - NIN; i2 = i1; mode = 1; }
    else                  { decode_pair(f - 2 * NIN, i1, i2); mode = 2; }
    const float wf = w[f];

    // Issue prefetch of tile 0 (rg = by) immediately.
    const float4* xv = reinterpret_cast<const float4*>(x);
    float4 p0, p1, p2, p3;
    {
        const size_t s0 = (size_t)by * BROWS * (NIN / 4);
        p0 = xv[s0 + 0 * TPB + tid];
        p1 = xv[s0 + 1 * TPB + tid];
        p2 = xv[s0 + 2 * TPB + tid];
        p3 = xv[s0 + 3 * TPB + tid];
    }

    // Tail features (f in [8192,8384)) for rows [wid*8, wid*8+8): 6 stores
    // per thread, x read direct from L2. Overlaps the tile-0 load latency.
#pragma unroll
    for (int q = 0; q < 6; ++q) {
        const int e  = q * TPB + tid;         // 0..1535
        const int r  = wid * 8 + e / NTAIL;
        const int ft = FMAIN + e % NTAIL;
        int ti, tj; decode_pair(ft - 2 * NIN, ti, tj);
        const float xi = x[(size_t)r * NIN + ti];
        const float xj = x[(size_t)r * NIN + tj];
        float p = xi * xj; p *= 0.5f;
        out[(size_t)r * NFEAT + ft] = p * w[ft];
    }

    // Commit tile 0 to LDS.
    float4* xsv = reinterpret_cast<float4*>(xs);
    xsv[0 * TPB + tid] = p0; xsv[1 * TPB + tid] = p1;
    xsv[2 * TPB + tid] = p2; xsv[3 * TPB + tid] = p3;
    __syncthreads();

    for (int k = 0; k < NT; ++k) {
        // Issue next tile's loads before the store burst (latency hidden).
        if (k + 1 < NT) {
            const size_t sn = (size_t)(by + NBY * (k + 1)) * BROWS * (NIN / 4);
            p0 = xv[sn + 0 * TPB + tid];
            p1 = xv[sn + 1 * TPB + tid];
            p2 = xv[sn + 2 * TPB + tid];
            p3 = xv[sn + 3 * TPB + tid];
        }

        const int rg = by + NBY * k;
        float* op = out + (size_t)rg * BROWS * NFEAT + f;
#pragma unroll
        for (int b = 0; b < BROWS; ++b) {
            const float xi = xs[b * NIN + i1];
            const float xj = xs[b * NIN + i2];  // lane-stride-1: conflict-free
            float p = xi * xj;                  // squares & pairs
            if (mode == 1) p = xi;              // singles
            if (mode == 2) p *= 0.5f;           // pairs (ref fp order)
            op[(size_t)b * NFEAT] = p * wf;     // dword store
        }

        if (k + 1 < NT) {
            __syncthreads();  // all reads of xs done
            xsv[0 * TPB + tid] = p0; xsv[1 * TPB + tid] = p1;
            xsv[2 * TPB + tid] = p2; xsv[3 * TPB + tid] = p3;
            __syncthreads();  // xs ready for next tile
        }
    }
}

extern "C" void kernel_launch(void* const* d_in, const int* in_sizes, int n_in,
                              void* d_out, int out_size, void* d_ws, size_t ws_size,
                              hipStream_t stream) {
    const float* x = (const float*)d_in[0];  // [16384, 128]
    const float* w = (const float*)d_in[1];  // [8384]
    float*     out = (float*)d_out;          // [16384, 8384]

    cpl_kernel<<<dim3(NBLK), dim3(TPB), 0, stream>>>(x, w, out);
}